// Round 1
// baseline (935.036 us; speedup 1.0000x reference)
//
#include <hip/hip_runtime.h>
#include <cstdint>
#include <cstddef>

// Sizes (fixed by the problem)
// B=512, N=200, F=32, E=128, H=128, L=2, 4H=512
#define LEAK 0.01f

typedef _Float16 f16;
typedef __attribute__((ext_vector_type(8))) _Float16 f16x8;
typedef __attribute__((ext_vector_type(4))) float f32x4;

static __device__ __forceinline__ float sigm(float x) {
  // 1/(1+exp(-x)); rcp(inf)=0 so no clamp needed for the ranges here
  return __builtin_amdgcn_rcpf(1.0f + __expf(-x));
}
static __device__ __forceinline__ float tanh_f(float x) {
  float xc = fminf(15.0f, fmaxf(-15.0f, x));
  float e2 = __expf(2.0f * xc);
  return (e2 - 1.0f) * __builtin_amdgcn_rcpf(e2 + 1.0f);
}
static __device__ __forceinline__ unsigned short f2bf(float f) {
  unsigned u = __builtin_bit_cast(unsigned, f);
  u += 0x7fffu + ((u >> 16) & 1u);
  return (unsigned short)(u >> 16);
}
static __device__ __forceinline__ float bf2f(unsigned short h) {
  return __builtin_bit_cast(float, (unsigned)h << 16);
}
static __device__ __forceinline__ f16x8 pack8(float4 a, float4 b) {
  f16x8 r;
  r[0] = (f16)a.x; r[1] = (f16)a.y; r[2] = (f16)a.z; r[3] = (f16)a.w;
  r[4] = (f16)b.x; r[5] = (f16)b.y; r[6] = (f16)b.z; r[7] = (f16)b.w;
  return r;
}
#define MFMA16(a, b, c) __builtin_amdgcn_mfma_f32_16x16x32_f16((a), (b), (c), 0, 0, 0)

// ---------------------------------------------------------------------------
// k_emb: e[t][b][j] = leaky_relu(sum_k x[b][t][k]*w_emb[j][k] + b_emb[j]), f16
// grid=200 (one WG per t), block=256; each thread handles 2 batch rows.
// ---------------------------------------------------------------------------
__global__ __launch_bounds__(256) void k_emb(
    const float* __restrict__ x, const float* __restrict__ wemb,
    const float* __restrict__ bemb, f16* __restrict__ e) {
  const int t = blockIdx.x, tid = threadIdx.x;
  __shared__ __align__(16) float wl[128 * 32];
  __shared__ float bl[128];
  for (int idx = tid; idx < 1024; idx += 256)
    ((float4*)wl)[idx] = ((const float4*)wemb)[idx];
  if (tid < 128) bl[tid] = bemb[tid];

  float xa[32], xb[32];
  const float* xpa = x + ((size_t)tid * 200 + t) * 32;
  const float* xpb = x + ((size_t)(tid + 256) * 200 + t) * 32;
#pragma unroll
  for (int k4 = 0; k4 < 8; ++k4) {
    float4 va = *(const float4*)(xpa + k4 * 4);
    float4 vb = *(const float4*)(xpb + k4 * 4);
    xa[k4 * 4 + 0] = va.x; xa[k4 * 4 + 1] = va.y; xa[k4 * 4 + 2] = va.z; xa[k4 * 4 + 3] = va.w;
    xb[k4 * 4 + 0] = vb.x; xb[k4 * 4 + 1] = vb.y; xb[k4 * 4 + 2] = vb.z; xb[k4 * 4 + 3] = vb.w;
  }
  __syncthreads();

  f16* ea = e + ((size_t)t * 512 + tid) * 128;
  f16* eb = e + ((size_t)t * 512 + tid + 256) * 128;
  for (int j8 = 0; j8 < 16; ++j8) {
    f16x8 oa, ob;
#pragma unroll
    for (int jj = 0; jj < 8; ++jj) {
      int j = j8 * 8 + jj;
      float aa = bl[j], ab = bl[j];
#pragma unroll
      for (int k4 = 0; k4 < 8; ++k4) {
        float4 wv = *(const float4*)&wl[j * 32 + k4 * 4];
        aa += xa[k4 * 4 + 0] * wv.x + xa[k4 * 4 + 1] * wv.y +
              xa[k4 * 4 + 2] * wv.z + xa[k4 * 4 + 3] * wv.w;
        ab += xb[k4 * 4 + 0] * wv.x + xb[k4 * 4 + 1] * wv.y +
              xb[k4 * 4 + 2] * wv.z + xb[k4 * 4 + 3] * wv.w;
      }
      oa[jj] = (f16)(aa >= 0.f ? aa : LEAK * aa);
      ob[jj] = (f16)(ab >= 0.f ? ab : LEAK * ab);
    }
    *(f16x8*)(ea + j8 * 8) = oa;
    *(f16x8*)(eb + j8 * 8) = ob;
  }
}

// ---------------------------------------------------------------------------
// k_rec: one LSTM layer, 200 steps. grid=32 (batch tile of 16), block=256.
// Wave w owns gate columns w*32..w*32+31 of each of the 4 gate blocks.
// Wih/Whh fragments live in registers; h round-trips via LDS (f16).
// ---------------------------------------------------------------------------
__global__ __launch_bounds__(256, 1) void k_rec(
    const f16* __restrict__ e, const float* __restrict__ wih,
    const float* __restrict__ whh, const float* __restrict__ bih,
    const float* __restrict__ bhh, float* __restrict__ hws,
    float* __restrict__ cws, f16* __restrict__ hs, int layer) {
  const int bt = blockIdx.x, tid = threadIdx.x;
  const int w = tid >> 6, lane = tid & 63, q = lane >> 4, l16 = lane & 15;
  __shared__ __align__(16) f16 hlds[2][16][136];  // double-buffered h, padded

  // Weight B-fragments: B[k][n] = W[n][k]; n = lane&15 within tile, k = q*8+j
  f16x8 BI[8][4], BH[8][4];
  float bias[8];
#pragma unroll
  for (int ti = 0; ti < 8; ++ti) {
    int blk = ti >> 1, s = ti & 1;
    int n = blk * 128 + w * 32 + s * 16 + l16;
    bias[ti] = bih[n] + bhh[n];
#pragma unroll
    for (int kc = 0; kc < 4; ++kc) {
      int k0 = kc * 32 + q * 8;
      const float4* pi = (const float4*)(wih + n * 128 + k0);
      const float4* ph = (const float4*)(whh + n * 128 + k0);
      BI[ti][kc] = pack8(pi[0], pi[1]);
      BH[ti][kc] = pack8(ph[0], ph[1]);
    }
  }

  // state init
  f32x4 cst[2];
  if (layer == 0) {
    cst[0] = (f32x4){0.f, 0.f, 0.f, 0.f};
    cst[1] = (f32x4){0.f, 0.f, 0.f, 0.f};
    for (int idx = tid; idx < 2 * 16 * 136; idx += 256)
      ((f16*)hlds)[idx] = (f16)0.f;
  } else {
    const float* cp = cws + ((size_t)(bt * 4 + w) * 64 + lane) * 8;
    const float* hp = hws + ((size_t)(bt * 4 + w) * 64 + lane) * 8;
    cst[0] = *(const f32x4*)cp;
    cst[1] = *(const f32x4*)(cp + 4);
#pragma unroll
    for (int s = 0; s < 2; ++s)
#pragma unroll
      for (int r = 0; r < 4; ++r)
        hlds[1][q * 4 + r][w * 32 + s * 16 + l16] = (f16)hp[s * 4 + r];
  }
  __syncthreads();

  const f16* ebase = e + (size_t)(bt * 16 + l16) * 128 + q * 8;
  f16x8 ax[4];
#pragma unroll
  for (int kc = 0; kc < 4; ++kc) ax[kc] = *(const f16x8*)(ebase + kc * 32);

  f32x4 hk[2];
  for (int t = 0; t < 200; ++t) {
    // prefetch next x fragments (independent of recurrence chain)
    f16x8 axn[4];
    {
      int tn = (t < 199) ? t + 1 : 199;
      const f16* ebn = ebase + (size_t)tn * 512 * 128;
#pragma unroll
      for (int kc = 0; kc < 4; ++kc) axn[kc] = *(const f16x8*)(ebn + kc * 32);
    }
    // h A-fragments from LDS
    const int rb = (t + 1) & 1;
    f16x8 ah[4];
#pragma unroll
    for (int kc = 0; kc < 4; ++kc)
      ah[kc] = *(const f16x8*)&hlds[rb][l16][kc * 32 + q * 8];

    f32x4 acc[8];
#pragma unroll
    for (int ti = 0; ti < 8; ++ti)
      acc[ti] = (f32x4){bias[ti], bias[ti], bias[ti], bias[ti]};
#pragma unroll
    for (int kc = 0; kc < 4; ++kc)
#pragma unroll
      for (int ti = 0; ti < 8; ++ti)
        acc[ti] = MFMA16(ax[kc], BI[ti][kc], acc[ti]);
#pragma unroll
    for (int kc = 0; kc < 4; ++kc)
#pragma unroll
      for (int ti = 0; ti < 8; ++ti)
        acc[ti] = MFMA16(ah[kc], BH[ti][kc], acc[ti]);

    // gates: ti = block*2+s -> i=acc[s], f=acc[2+s], g=acc[4+s], o=acc[6+s]
    const int wb = t & 1;
    f16x8 hpk;
#pragma unroll
    for (int s = 0; s < 2; ++s) {
      f32x4 iv = acc[0 + s], fv = acc[2 + s], gv = acc[4 + s], ov = acc[6 + s];
#pragma unroll
      for (int r = 0; r < 4; ++r) {
        float cc = sigm(fv[r]) * cst[s][r] + sigm(iv[r]) * tanh_f(gv[r]);
        float hv = sigm(ov[r]) * tanh_f(cc);
        cst[s][r] = cc;
        hk[s][r] = hv;
        hlds[wb][q * 4 + r][w * 32 + s * 16 + l16] = (f16)hv;
        hpk[s * 4 + r] = (f16)hv;
      }
    }
    if (layer != 0) {
      *(f16x8*)(hs + ((size_t)((t * 32 + bt) * 4 + w) * 64 + lane) * 8) = hpk;
    }
#pragma unroll
    for (int kc = 0; kc < 4; ++kc) ax[kc] = axn[kc];
    __syncthreads();
  }

  float* hp = hws + ((size_t)(bt * 4 + w) * 64 + lane) * 8;
  float* cp = cws + ((size_t)(bt * 4 + w) * 64 + lane) * 8;
  *(f32x4*)hp = hk[0];
  *(f32x4*)(hp + 4) = hk[1];
  *(f32x4*)cp = cst[0];
  *(f32x4*)(cp + 4) = cst[1];
}

// ---------------------------------------------------------------------------
// k_fc1: out1[b][t][:] = leaky_relu(hs[t][b][:] @ w_fc1^T + b_fc1), f16 out.
// grid = 200*8 (t, 64-row group), block = 256.
// ---------------------------------------------------------------------------
__global__ __launch_bounds__(256) void k_fc1(
    const f16* __restrict__ hs, const float* __restrict__ wfc1,
    const float* __restrict__ bfc1, f16* __restrict__ out1) {
  const int g = blockIdx.x;
  const int t = g >> 3, rg = g & 7;
  const int tid = threadIdx.x;
  const int w = tid >> 6, lane = tid & 63, q = lane >> 4, l16 = lane & 15;
  __shared__ __align__(16) f16 st[64][136];

  // stage hs fragments -> LDS rows
#pragma unroll
  for (int u = 0; u < 4; ++u) {
    f16x8 v = *(const f16x8*)(hs + ((size_t)((t * 32 + rg * 4 + u) * 4 + w) * 64 + lane) * 8);
#pragma unroll
    for (int s = 0; s < 2; ++s)
#pragma unroll
      for (int r = 0; r < 4; ++r)
        st[u * 16 + q * 4 + r][w * 32 + s * 16 + l16] = v[s * 4 + r];
  }
  // B fragments for this wave's 32 output cols
  f16x8 BF[2][4];
  float bias[2];
#pragma unroll
  for (int s = 0; s < 2; ++s) {
    int n = w * 32 + s * 16 + l16;
    bias[s] = bfc1[n];
#pragma unroll
    for (int kc = 0; kc < 4; ++kc) {
      const float4* p = (const float4*)(wfc1 + n * 128 + kc * 32 + q * 8);
      BF[s][kc] = pack8(p[0], p[1]);
    }
  }
  __syncthreads();

#pragma unroll
  for (int u = 0; u < 4; ++u) {
    f16x8 af[4];
#pragma unroll
    for (int kc = 0; kc < 4; ++kc)
      af[kc] = *(const f16x8*)&st[u * 16 + l16][kc * 32 + q * 8];
    f32x4 acc0 = (f32x4){bias[0], bias[0], bias[0], bias[0]};
    f32x4 acc1 = (f32x4){bias[1], bias[1], bias[1], bias[1]};
#pragma unroll
    for (int kc = 0; kc < 4; ++kc) {
      acc0 = MFMA16(af[kc], BF[0][kc], acc0);
      acc1 = MFMA16(af[kc], BF[1][kc], acc1);
    }
    int brow = rg * 64 + u * 16 + q * 4;
#pragma unroll
    for (int r = 0; r < 4; ++r) {
      float v0 = acc0[r]; v0 = v0 >= 0.f ? v0 : LEAK * v0;
      float v1 = acc1[r]; v1 = v1 >= 0.f ? v1 : LEAK * v1;
      out1[((size_t)(brow + r) * 200 + t) * 128 + w * 32 + 0 * 16 + l16] = (f16)v0;
      out1[((size_t)(brow + r) * 200 + t) * 128 + w * 32 + 1 * 16 + l16] = (f16)v1;
    }
  }
}

// ---------------------------------------------------------------------------
// k_fc2: per-batch fused  M = out1[b]@w_fc2^T + b_fc2 ; E=exp(M) in LDS(bf16);
// Sinkhorn scalings u,v (5 iters); psi = u_i * E_ij * v_j.
// grid=512, block=256, dynamic LDS = 85600 B.
// ---------------------------------------------------------------------------
__global__ __launch_bounds__(256) void k_fc2(
    const f16* __restrict__ out1, const float* __restrict__ wfc2,
    const float* __restrict__ bfc2, float* __restrict__ psi) {
  extern __shared__ char smem[];
  unsigned short* E = (unsigned short*)smem;      // [200][210] bf16 bits
  float* uu = (float*)(smem + 84000);             // [200]
  float* vv = (float*)(smem + 84800);             // [200]
  const int b = blockIdx.x, tid = threadIdx.x;
  const int w = tid >> 6, lane = tid & 63, q = lane >> 4, l16 = lane & 15;
  const f16* A = out1 + (size_t)b * 200 * 128;

  f16x8 BF[4][4];
  float bias[4] = {0.f, 0.f, 0.f, 0.f};
#pragma unroll
  for (int ci = 0; ci < 4; ++ci) {
    int ct = w + ci * 4;
    if (ct < 13) {
      int n = ct * 16 + l16; if (n > 199) n = 199;
      bias[ci] = bfc2[n];
#pragma unroll
      for (int kc = 0; kc < 4; ++kc) {
        const float4* p = (const float4*)(wfc2 + n * 128 + kc * 32 + q * 8);
        BF[ci][kc] = pack8(p[0], p[1]);
      }
    }
  }
  for (int rt = 0; rt < 13; ++rt) {
    int m = rt * 16 + l16; if (m > 199) m = 199;
    f16x8 af[4];
#pragma unroll
    for (int kc = 0; kc < 4; ++kc)
      af[kc] = *(const f16x8*)(A + (size_t)m * 128 + kc * 32 + q * 8);
#pragma unroll
    for (int ci = 0; ci < 4; ++ci) {
      int ct = w + ci * 4;
      if (ct < 13) {
        f32x4 acc = (f32x4){bias[ci], bias[ci], bias[ci], bias[ci]};
#pragma unroll
        for (int kc = 0; kc < 4; ++kc) acc = MFMA16(af[kc], BF[ci][kc], acc);
        int col = ct * 16 + l16;
#pragma unroll
        for (int r = 0; r < 4; ++r) {
          int row = rt * 16 + q * 4 + r;
          if (row < 200 && col < 200) E[row * 210 + col] = f2bf(__expf(acc[r]));
        }
      }
    }
  }
  if (tid < 200) vv[tid] = 1.0f;
  __syncthreads();

  for (int it = 0; it < 5; ++it) {
    if (tid < 200) {
      const unsigned short* Er = E + tid * 210;
      float s0 = 0.f, s1 = 0.f, s2 = 0.f, s3 = 0.f;
      for (int j = 0; j < 200; j += 4) {
        s0 += bf2f(Er[j + 0]) * vv[j + 0];
        s1 += bf2f(Er[j + 1]) * vv[j + 1];
        s2 += bf2f(Er[j + 2]) * vv[j + 2];
        s3 += bf2f(Er[j + 3]) * vv[j + 3];
      }
      uu[tid] = __builtin_amdgcn_rcpf((s0 + s1) + (s2 + s3));
    }
    __syncthreads();
    if (tid < 200) {
      float s0 = 0.f, s1 = 0.f, s2 = 0.f, s3 = 0.f;
      for (int i = 0; i < 200; i += 4) {
        s0 += bf2f(E[(i + 0) * 210 + tid]) * uu[i + 0];
        s1 += bf2f(E[(i + 1) * 210 + tid]) * uu[i + 1];
        s2 += bf2f(E[(i + 2) * 210 + tid]) * uu[i + 2];
        s3 += bf2f(E[(i + 3) * 210 + tid]) * uu[i + 3];
      }
      vv[tid] = __builtin_amdgcn_rcpf((s0 + s1) + (s2 + s3));
    }
    __syncthreads();
  }

  float* P = psi + (size_t)b * 40000;
  for (int idx = tid; idx < 40000; idx += 256) {
    unsigned i = ((unsigned)idx * 5243u) >> 20;   // idx / 200
    unsigned j = (unsigned)idx - i * 200u;
    P[idx] = uu[i] * bf2f(E[i * 210 + j]) * vv[j];
  }
}

// ---------------------------------------------------------------------------
extern "C" void kernel_launch(void* const* d_in, const int* in_sizes, int n_in,
                              void* d_out, int out_size, void* d_ws, size_t ws_size,
                              hipStream_t stream) {
  const float* x    = (const float*)d_in[0];
  const float* wemb = (const float*)d_in[1];
  const float* bemb = (const float*)d_in[2];
  const float* wih  = (const float*)d_in[3];
  const float* whh  = (const float*)d_in[4];
  const float* bih  = (const float*)d_in[5];
  const float* bhh  = (const float*)d_in[6];
  const float* wfc1 = (const float*)d_in[7];
  const float* bfc1 = (const float*)d_in[8];
  const float* wfc2 = (const float*)d_in[9];
  const float* bfc2 = (const float*)d_in[10];
  float* psi = (float*)d_out;

  char* ws = (char*)d_ws;
  f16*   e    = (f16*)(ws);                 // [200][512][128] f16  = 26,214,400 B
  f16*   hs   = (f16*)(ws + 26214400);      // frag layout          = 26,214,400 B
  float* hws  = (float*)(ws + 52428800);    // [32][4][64][8] f32   =    262,144 B
  float* cws  = (float*)(ws + 52690944);    //                      =    262,144 B
  f16*   out1 = (f16*)(ws + 52953088);      // [512][200][128] f16  = 26,214,400 B
  // total ws use: 79,167,488 B

  (void)hipFuncSetAttribute((const void*)k_fc2,
                            hipFuncAttributeMaxDynamicSharedMemorySize, 85600);

  k_emb<<<200, 256, 0, stream>>>(x, wemb, bemb, e);
  k_rec<<<32, 256, 0, stream>>>(e, wih, whh, bih, bhh, hws, cws, hs, 0);
  k_rec<<<32, 256, 0, stream>>>(e, wih + 65536, whh + 65536, bih + 512, bhh + 512,
                                hws, cws, hs, 1);
  k_fc1<<<1600, 256, 0, stream>>>(hs, wfc1, bfc1, out1);
  k_fc2<<<512, 256, 85600, stream>>>(out1, wfc2, bfc2, psi);
}

// Round 2
// 791.272 us; speedup vs baseline: 1.1817x; 1.1817x over previous
//
#include <hip/hip_runtime.h>
#include <cstdint>
#include <cstddef>

// Sizes (fixed): B=512, N=200, F=32, E=H=128, L=2, 4H=512
#define LEAK 0.01f

typedef _Float16 f16;
typedef __attribute__((ext_vector_type(4))) _Float16 f16x4;
typedef __attribute__((ext_vector_type(8))) _Float16 f16x8;
typedef __attribute__((ext_vector_type(4))) float f32x4;

static __device__ __forceinline__ float sigm(float x) {
  return __builtin_amdgcn_rcpf(1.0f + __expf(-x));
}
static __device__ __forceinline__ float tanh_f(float x) {
  float xc = fminf(15.0f, fmaxf(-15.0f, x));
  float e2 = __expf(2.0f * xc);
  return (e2 - 1.0f) * __builtin_amdgcn_rcpf(e2 + 1.0f);
}
static __device__ __forceinline__ unsigned short f2bf(float f) {
  unsigned u = __builtin_bit_cast(unsigned, f);
  u += 0x7fffu + ((u >> 16) & 1u);
  return (unsigned short)(u >> 16);
}
static __device__ __forceinline__ float bf2f(unsigned short h) {
  return __builtin_bit_cast(float, (unsigned)h << 16);
}
static __device__ __forceinline__ f16x8 pack8(float4 a, float4 b) {
  f16x8 r;
  r[0] = (f16)a.x; r[1] = (f16)a.y; r[2] = (f16)a.z; r[3] = (f16)a.w;
  r[4] = (f16)b.x; r[5] = (f16)b.y; r[6] = (f16)b.z; r[7] = (f16)b.w;
  return r;
}
#define MFMA16(a, b, c) __builtin_amdgcn_mfma_f32_16x16x32_f16((a), (b), (c), 0, 0, 0)

// ---------------------------------------------------------------------------
// k_emb: e[t][b][j] = leaky_relu(x[b][t][:] . w_emb[j][:] + b_emb[j]), f16
// grid=200 (one WG per t), block=256; each thread handles 2 batch rows.
// ---------------------------------------------------------------------------
__global__ __launch_bounds__(256) void k_emb(
    const float* __restrict__ x, const float* __restrict__ wemb,
    const float* __restrict__ bemb, f16* __restrict__ e) {
  const int t = blockIdx.x, tid = threadIdx.x;
  __shared__ __align__(16) float wl[128 * 32];
  __shared__ float bl[128];
  for (int idx = tid; idx < 1024; idx += 256)
    ((float4*)wl)[idx] = ((const float4*)wemb)[idx];
  if (tid < 128) bl[tid] = bemb[tid];

  float xa[32], xb[32];
  const float* xpa = x + ((size_t)tid * 200 + t) * 32;
  const float* xpb = x + ((size_t)(tid + 256) * 200 + t) * 32;
#pragma unroll
  for (int k4 = 0; k4 < 8; ++k4) {
    float4 va = *(const float4*)(xpa + k4 * 4);
    float4 vb = *(const float4*)(xpb + k4 * 4);
    xa[k4 * 4 + 0] = va.x; xa[k4 * 4 + 1] = va.y; xa[k4 * 4 + 2] = va.z; xa[k4 * 4 + 3] = va.w;
    xb[k4 * 4 + 0] = vb.x; xb[k4 * 4 + 1] = vb.y; xb[k4 * 4 + 2] = vb.z; xb[k4 * 4 + 3] = vb.w;
  }
  __syncthreads();

  f16* ea = e + ((size_t)t * 512 + tid) * 128;
  f16* eb = e + ((size_t)t * 512 + tid + 256) * 128;
  for (int j8 = 0; j8 < 16; ++j8) {
    f16x8 oa, ob;
#pragma unroll
    for (int jj = 0; jj < 8; ++jj) {
      int j = j8 * 8 + jj;
      float aa = bl[j], ab = bl[j];
#pragma unroll
      for (int k4 = 0; k4 < 8; ++k4) {
        float4 wv = *(const float4*)&wl[j * 32 + k4 * 4];
        aa += xa[k4 * 4 + 0] * wv.x + xa[k4 * 4 + 1] * wv.y +
              xa[k4 * 4 + 2] * wv.z + xa[k4 * 4 + 3] * wv.w;
        ab += xb[k4 * 4 + 0] * wv.x + xb[k4 * 4 + 1] * wv.y +
              xb[k4 * 4 + 2] * wv.z + xb[k4 * 4 + 3] * wv.w;
      }
      oa[jj] = (f16)(aa >= 0.f ? aa : LEAK * aa);
      ob[jj] = (f16)(ab >= 0.f ? ab : LEAK * ab);
    }
    *(f16x8*)(ea + j8 * 8) = oa;
    *(f16x8*)(eb + j8 * 8) = ob;
  }
}

// ---------------------------------------------------------------------------
// k_rec: one LSTM layer, 200 steps. grid=32 (batch tile 16), block=512.
// 8 waves; wave w owns hidden units n = w*16..w*16+15 for ALL 4 gates
// (self-contained cell update). 32 MFMAs + 4 cell updates per thread-step.
// 2 waves/SIMD (launch_bounds(512,2)) to hide latency.
// ---------------------------------------------------------------------------
__global__ __launch_bounds__(512, 2) void k_rec(
    const f16* __restrict__ e, const float* __restrict__ wih,
    const float* __restrict__ whh, const float* __restrict__ bih,
    const float* __restrict__ bhh, float* __restrict__ hws,
    float* __restrict__ cws, f16* __restrict__ hs, int layer) {
  const int bt = blockIdx.x, tid = threadIdx.x;
  const int w = tid >> 6, lane = tid & 63, q = lane >> 4, l16 = lane & 15;
  __shared__ __align__(16) f16 hlds[2][16][136];  // double-buffered h, padded

  // B-fragments: B[k][n], n = G*128 + w*16 + l16, k = kc*32 + q*8 + j
  f16x8 BI[4][4], BH[4][4];
  float bias[4];
#pragma unroll
  for (int G = 0; G < 4; ++G) {
    int n = G * 128 + w * 16 + l16;
    bias[G] = bih[n] + bhh[n];
#pragma unroll
    for (int kc = 0; kc < 4; ++kc) {
      int k0 = kc * 32 + q * 8;
      const float4* pi = (const float4*)(wih + (size_t)n * 128 + k0);
      const float4* ph = (const float4*)(whh + (size_t)n * 128 + k0);
      BI[G][kc] = pack8(pi[0], pi[1]);
      BH[G][kc] = pack8(ph[0], ph[1]);
    }
  }

  // state init
  f32x4 cst;
  if (layer == 0) {
    cst = (f32x4){0.f, 0.f, 0.f, 0.f};
    for (int idx = tid; idx < 2 * 16 * 136; idx += 512)
      ((f16*)hlds)[idx] = (f16)0.f;
  } else {
    const float* cp = cws + ((size_t)(bt * 8 + w) * 64 + lane) * 4;
    const float* hp = hws + ((size_t)(bt * 8 + w) * 64 + lane) * 4;
    cst = *(const f32x4*)cp;
    f32x4 hv = *(const f32x4*)hp;
#pragma unroll
    for (int r = 0; r < 4; ++r)
      hlds[1][q * 4 + r][w * 16 + l16] = (f16)hv[r];
  }
  __syncthreads();

  const f16* ebase = e + (size_t)(bt * 16 + l16) * 128 + q * 8;
  f16x8 ax[4];
#pragma unroll
  for (int kc = 0; kc < 4; ++kc) ax[kc] = *(const f16x8*)(ebase + kc * 32);

  f32x4 hk;
  const int srow = tid >> 5, scol = (tid & 31) * 4;  // coalesced hs store map
  for (int t = 0; t < 200; ++t) {
    // prefetch next x fragments (independent of recurrence chain)
    f16x8 axn[4];
    {
      int tn = (t < 199) ? t + 1 : 199;
      const f16* ebn = ebase + (size_t)tn * 512 * 128;
#pragma unroll
      for (int kc = 0; kc < 4; ++kc) axn[kc] = *(const f16x8*)(ebn + kc * 32);
    }
    // h A-fragments from LDS
    const int rb = (t + 1) & 1;
    f16x8 ah[4];
#pragma unroll
    for (int kc = 0; kc < 4; ++kc)
      ah[kc] = *(const f16x8*)&hlds[rb][l16][kc * 32 + q * 8];

    f32x4 acc[4];
#pragma unroll
    for (int G = 0; G < 4; ++G)
      acc[G] = (f32x4){bias[G], bias[G], bias[G], bias[G]};
#pragma unroll
    for (int kc = 0; kc < 4; ++kc)
#pragma unroll
      for (int G = 0; G < 4; ++G)
        acc[G] = MFMA16(ax[kc], BI[G][kc], acc[G]);
#pragma unroll
    for (int kc = 0; kc < 4; ++kc)
#pragma unroll
      for (int G = 0; G < 4; ++G)
        acc[G] = MFMA16(ah[kc], BH[G][kc], acc[G]);

    const int wb = t & 1;
#pragma unroll
    for (int r = 0; r < 4; ++r) {
      float cc = sigm(acc[1][r]) * cst[r] + sigm(acc[0][r]) * tanh_f(acc[2][r]);
      float hv = sigm(acc[3][r]) * tanh_f(cc);
      cst[r] = cc;
      hk[r] = hv;
      hlds[wb][q * 4 + r][w * 16 + l16] = (f16)hv;
    }
    __syncthreads();
    if (layer != 0) {
      // coalesced readback: thread -> (row srow, cols scol..scol+3)
      f16x4 hv4 = *(const f16x4*)&hlds[wb][srow][scol];
      *(f16x4*)(hs + ((size_t)(bt * 16 + srow) * 200 + t) * 128 + scol) = hv4;
    }
#pragma unroll
    for (int kc = 0; kc < 4; ++kc) ax[kc] = axn[kc];
  }

  float* hp = hws + ((size_t)(bt * 8 + w) * 64 + lane) * 4;
  float* cp = cws + ((size_t)(bt * 8 + w) * 64 + lane) * 4;
  *(f32x4*)hp = hk;
  *(f32x4*)cp = cst;
}

// ---------------------------------------------------------------------------
// k_head: per-batch fused fc1 -> leaky -> fc2 -> exp -> Sinkhorn -> psi.
// grid=512 (one WG per batch), block=256, dynamic LDS = 140000 B:
//   E    [200][210] bf16 bits @ 0       (84000 B)
//   out1 [200][136] f16       @ 84000   (54400 B)
//   uu   [200] f32            @ 138400
//   vv   [200] f32            @ 139200
// ---------------------------------------------------------------------------
__global__ __launch_bounds__(256) void k_head(
    const f16* __restrict__ hs, const float* __restrict__ wfc1,
    const float* __restrict__ bfc1, const float* __restrict__ wfc2,
    const float* __restrict__ bfc2, float* __restrict__ psi) {
  extern __shared__ char smem[];
  unsigned short* E = (unsigned short*)smem;
  f16* o1 = (f16*)(smem + 84000);
  float* uu = (float*)(smem + 138400);
  float* vv = (float*)(smem + 139200);
  const int b = blockIdx.x, tid = threadIdx.x;
  const int w = tid >> 6, lane = tid & 63, q = lane >> 4, l16 = lane & 15;
  const f16* A = hs + (size_t)b * 200 * 128;

  // fc1 B-fragments: wave w owns cols w*32 + s*16 + l16
  f16x8 BF1[2][4];
  float bias1[2];
#pragma unroll
  for (int s = 0; s < 2; ++s) {
    int n = w * 32 + s * 16 + l16;
    bias1[s] = bfc1[n];
#pragma unroll
    for (int kc = 0; kc < 4; ++kc) {
      const float4* p = (const float4*)(wfc1 + (size_t)n * 128 + kc * 32 + q * 8);
      BF1[s][kc] = pack8(p[0], p[1]);
    }
  }
  // fc2 B-fragments: wave w owns col tiles ct = w + ci*4 (ct < 13)
  f16x8 BF2[4][4];
  float bias2[4] = {0.f, 0.f, 0.f, 0.f};
#pragma unroll
  for (int ci = 0; ci < 4; ++ci) {
    int ct = w + ci * 4;
    if (ct < 13) {
      int n = ct * 16 + l16; if (n > 199) n = 199;
      bias2[ci] = bfc2[n];
#pragma unroll
      for (int kc = 0; kc < 4; ++kc) {
        const float4* p = (const float4*)(wfc2 + (size_t)n * 128 + kc * 32 + q * 8);
        BF2[ci][kc] = pack8(p[0], p[1]);
      }
    }
  }

  // ---- fc1: out1 = leaky(hs[b] @ W1^T + b1), A-frags straight from global
  for (int rt = 0; rt < 13; ++rt) {
    int m = rt * 16 + l16; if (m > 199) m = 199;
    f16x8 af[4];
#pragma unroll
    for (int kc = 0; kc < 4; ++kc)
      af[kc] = *(const f16x8*)(A + (size_t)m * 128 + kc * 32 + q * 8);
#pragma unroll
    for (int s = 0; s < 2; ++s) {
      f32x4 acc = (f32x4){bias1[s], bias1[s], bias1[s], bias1[s]};
#pragma unroll
      for (int kc = 0; kc < 4; ++kc) acc = MFMA16(af[kc], BF1[s][kc], acc);
      int col = w * 32 + s * 16 + l16;
#pragma unroll
      for (int r = 0; r < 4; ++r) {
        int row = rt * 16 + q * 4 + r;
        float v = acc[r]; v = v >= 0.f ? v : LEAK * v;
        if (row < 200) o1[row * 136 + col] = (f16)v;
      }
    }
  }
  __syncthreads();

  // ---- fc2 + exp -> E
  for (int rt = 0; rt < 13; ++rt) {
    int m = rt * 16 + l16; if (m > 199) m = 199;
    f16x8 af[4];
#pragma unroll
    for (int kc = 0; kc < 4; ++kc)
      af[kc] = *(const f16x8*)&o1[m * 136 + kc * 32 + q * 8];
#pragma unroll
    for (int ci = 0; ci < 4; ++ci) {
      int ct = w + ci * 4;
      if (ct < 13) {
        f32x4 acc = (f32x4){bias2[ci], bias2[ci], bias2[ci], bias2[ci]};
#pragma unroll
        for (int kc = 0; kc < 4; ++kc) acc = MFMA16(af[kc], BF2[ci][kc], acc);
        int col = ct * 16 + l16;
#pragma unroll
        for (int r = 0; r < 4; ++r) {
          int row = rt * 16 + q * 4 + r;
          if (row < 200 && col < 200) E[row * 210 + col] = f2bf(__expf(acc[r]));
        }
      }
    }
  }
  if (tid < 200) vv[tid] = 1.0f;
  __syncthreads();

  // ---- Sinkhorn scalings: u = 1/(E v), v = 1/(E^T u), 5 iters
  for (int it = 0; it < 5; ++it) {
    if (tid < 200) {
      const unsigned short* Er = E + tid * 210;
      float s0 = 0.f, s1 = 0.f, s2 = 0.f, s3 = 0.f;
      for (int j = 0; j < 200; j += 4) {
        s0 += bf2f(Er[j + 0]) * vv[j + 0];
        s1 += bf2f(Er[j + 1]) * vv[j + 1];
        s2 += bf2f(Er[j + 2]) * vv[j + 2];
        s3 += bf2f(Er[j + 3]) * vv[j + 3];
      }
      uu[tid] = __builtin_amdgcn_rcpf((s0 + s1) + (s2 + s3));
    }
    __syncthreads();
    if (tid < 200) {
      float s0 = 0.f, s1 = 0.f, s2 = 0.f, s3 = 0.f;
      for (int i = 0; i < 200; i += 4) {
        s0 += bf2f(E[(i + 0) * 210 + tid]) * uu[i + 0];
        s1 += bf2f(E[(i + 1) * 210 + tid]) * uu[i + 1];
        s2 += bf2f(E[(i + 2) * 210 + tid]) * uu[i + 2];
        s3 += bf2f(E[(i + 3) * 210 + tid]) * uu[i + 3];
      }
      vv[tid] = __builtin_amdgcn_rcpf((s0 + s1) + (s2 + s3));
    }
    __syncthreads();
  }

  // ---- psi = u_i * E_ij * v_j
  float* P = psi + (size_t)b * 40000;
  for (int idx = tid; idx < 40000; idx += 256) {
    unsigned i = ((unsigned)idx * 5243u) >> 20;   // idx / 200
    unsigned j = (unsigned)idx - i * 200u;
    P[idx] = uu[i] * bf2f(E[i * 210 + j]) * vv[j];
  }
}

// ---------------------------------------------------------------------------
extern "C" void kernel_launch(void* const* d_in, const int* in_sizes, int n_in,
                              void* d_out, int out_size, void* d_ws, size_t ws_size,
                              hipStream_t stream) {
  const float* x    = (const float*)d_in[0];
  const float* wemb = (const float*)d_in[1];
  const float* bemb = (const float*)d_in[2];
  const float* wih  = (const float*)d_in[3];
  const float* whh  = (const float*)d_in[4];
  const float* bih  = (const float*)d_in[5];
  const float* bhh  = (const float*)d_in[6];
  const float* wfc1 = (const float*)d_in[7];
  const float* bfc1 = (const float*)d_in[8];
  const float* wfc2 = (const float*)d_in[9];
  const float* bfc2 = (const float*)d_in[10];
  float* psi = (float*)d_out;

  char* ws = (char*)d_ws;
  f16*   e   = (f16*)(ws);                  // [200][512][128] f16 = 26,214,400 B
  float* hws = (float*)(ws + 26214400);     // [32*8*64*4] f32     =    262,144 B
  float* cws = (float*)(ws + 26476544);     //                     =    262,144 B
  f16*   hs  = (f16*)(ws + 26738688);       // [512][200][128] f16 = 26,214,400 B
  // total ws use: 52,953,088 B

  (void)hipFuncSetAttribute((const void*)k_head,
                            hipFuncAttributeMaxDynamicSharedMemorySize, 140000);

  k_emb<<<200, 256, 0, stream>>>(x, wemb, bemb, e);
  k_rec<<<32, 512, 0, stream>>>(e, wih, whh, bih, bhh, hws, cws, hs, 0);
  k_rec<<<32, 512, 0, stream>>>(e, wih + 65536, whh + 65536, bih + 512, bhh + 512,
                                hws, cws, hs, 1);
  k_head<<<512, 256, 140000, stream>>>(hs, wfc1, bfc1, wfc2, bfc2, psi);
}